// Round 4
// baseline (300.521 us; speedup 1.0000x reference)
//
#include <hip/hip_runtime.h>
#include <cstdint>
#include <cstddef>

#define N 1024
#define HN 4
#define FDIM 64
#define KSEL 512
#define FLT_MAX_ 3.402823466e+38f

// ---------------- reduction helpers (blockDim.x == 256) ----------------
__device__ __forceinline__ float wred_sum(float v){
#pragma unroll
  for(int o=32;o>0;o>>=1) v += __shfl_down(v,o,64);
  return v;
}
__device__ __forceinline__ float wred_max(float v){
#pragma unroll
  for(int o=32;o>0;o>>=1) v = fmaxf(v,__shfl_down(v,o,64));
  return v;
}
__device__ __forceinline__ float bred_sum(float v, float* scr){
  int t=threadIdx.x;
  v = wred_sum(v);
  __syncthreads();
  if((t&63)==0) scr[t>>6]=v;
  __syncthreads();
  return (scr[0]+scr[1])+(scr[2]+scr[3]);
}
__device__ __forceinline__ float bred_max(float v, float* scr){
  int t=threadIdx.x;
  v = wred_max(v);
  __syncthreads();
  if((t&63)==0) scr[t>>6]=v;
  __syncthreads();
  return fmaxf(fmaxf(scr[0],scr[1]),fmaxf(scr[2],scr[3]));
}

// ---------------- K0: zero masks ----------------
__global__ __launch_bounds__(256) void zero_ints(int* p, int n){
  int i = blockIdx.x*256 + threadIdx.x;
  if(i<n) p[i]=0;
}

// ---------------- K1: g = x@W ----------------
__global__ __launch_bounds__(256) void gemm_lr(const float* __restrict__ x,
                                               const float* __restrict__ W_l,
                                               const float* __restrict__ W_r,
                                               float* __restrict__ g_l,
                                               float* __restrict__ g_r){
  int i0 = blockIdx.x*4, t = threadIdx.x;
  const float* __restrict__ W = blockIdx.y ? W_r : W_l;
  float* __restrict__ g = blockIdx.y ? g_r : g_l;
  float acc[4] = {0.f,0.f,0.f,0.f};
#pragma unroll 8
  for(int k=0;k<256;k++){
    float w = W[(size_t)k*256 + t];
#pragma unroll
    for(int r=0;r<4;r++) acc[r] = fmaf(x[(size_t)(i0+r)*256 + k], w, acc[r]);
  }
#pragma unroll
  for(int r=0;r<4;r++) g[(size_t)(i0+r)*256 + t] = acc[r];
}

// ---------------- K2p/K2f/K2n: min/max + norms ----------------
__global__ __launch_bounds__(256) void colmm_part(const float* __restrict__ feats,
                                                  const float* __restrict__ g_r,
                                                  float* __restrict__ pmin_f, float* __restrict__ pmax_f,
                                                  float* __restrict__ pmin_g, float* __restrict__ pmax_g){
  int chunk = blockIdx.x, src = blockIdx.y, t = threadIdx.x;
  int cols = src ? 256 : 128;
  const float* in = src ? g_r : feats;
  if(t < cols){
    float lo = FLT_MAX_, hi = -FLT_MAX_;
    int r0 = chunk*64;
    for(int r=0;r<64;r++){
      float v = in[(size_t)(r0+r)*cols + t];
      lo = fminf(lo,v); hi = fmaxf(hi,v);
    }
    if(src){ pmin_g[chunk*256+t]=lo; pmax_g[chunk*256+t]=hi; }
    else   { pmin_f[chunk*128+t]=lo; pmax_f[chunk*128+t]=hi; }
  }
}

__global__ __launch_bounds__(256) void colmm_fin(const float* __restrict__ pmin_f, const float* __restrict__ pmax_f,
                                                 const float* __restrict__ pmin_g, const float* __restrict__ pmax_g,
                                                 float* __restrict__ fmn, float* __restrict__ fmx,
                                                 float* __restrict__ gmn, float* __restrict__ gmx){
  int src = blockIdx.x, t = threadIdx.x;
  int cols = src ? 256 : 128;
  if(t < cols){
    float lo = FLT_MAX_, hi = -FLT_MAX_;
    const float* pn = src ? pmin_g : pmin_f;
    const float* px = src ? pmax_g : pmax_f;
    for(int k=0;k<16;k++){
      lo = fminf(lo, pn[k*cols+t]);
      hi = fmaxf(hi, px[k*cols+t]);
    }
    if(src){ gmn[t]=lo; gmx[t]=hi; } else { fmn[t]=lo; fmx[t]=hi; }
  }
}

__global__ __launch_bounds__(256) void norms_kernel(const float* __restrict__ feats,
                                                    const float* __restrict__ g_r,
                                                    const float* __restrict__ fmn, const float* __restrict__ fmx,
                                                    const float* __restrict__ gmn, const float* __restrict__ gmx,
                                                    float* __restrict__ nf, float* __restrict__ ng){
  __shared__ float scr[4];
  int i = blockIdx.x, z = blockIdx.y, t = threadIdx.x;
  if(z==0){
    float u = 0.f;
    if(t < 128){
      float d = fmx[t]-fmn[t];
      float v = feats[(size_t)i*128 + t];
      u = (d==0.f) ? 0.f : (v - fmn[t])/d;
    }
    float tot = bred_sum(u*u, scr);
    if(t==0) nf[i] = sqrtf(tot);
  } else {
    int c = t, hh = t>>6;
    float d = gmx[c]-gmn[c];
    float v = g_r[(size_t)i*256 + c];
    float u = (v - gmn[c])/d;
    float ss = wred_sum(u*u);
    if((t&63)==0) ng[hh*N + i] = sqrtf(ss);
  }
}

// ---------------- K3: e[h][i][j] ----------------
__global__ __launch_bounds__(256) void compute_e(const float* __restrict__ g_l,
                                                 const float* __restrict__ g_r,
                                                 const float* __restrict__ attn_w,
                                                 float* __restrict__ e){
  __shared__ float grs[64][65];
  __shared__ float gls[64][65];
  __shared__ float aw[64], aw2[64];
  int h = blockIdx.z, i0 = blockIdx.y*64, j0 = blockIdx.x*64;
  int t = threadIdx.x;
  if(t < 64){ float w = attn_w[t]; aw[t]=w; aw2[t]=0.2f*w; }
#pragma unroll
  for(int k=0;k<16;k++){
    int idx = t + k*256; int r = idx>>6, f = idx&63;
    grs[r][f] = g_r[(size_t)(i0+r)*256 + h*64 + f];
    gls[r][f] = g_l[(size_t)(j0+r)*256 + h*64 + f];
  }
  __syncthreads();
  int tj = t&15, ti = t>>4;
  float acc[4][4];
#pragma unroll
  for(int a=0;a<4;a++)
#pragma unroll
    for(int b=0;b<4;b++) acc[a][b]=0.f;
  for(int f=0;f<64;f++){
    float w = aw[f], w2 = aw2[f];
    float ga[4], gb[4];
#pragma unroll
    for(int a=0;a<4;a++) ga[a] = grs[ti*4+a][f];
#pragma unroll
    for(int b=0;b<4;b++) gb[b] = gls[tj+16*b][f];
#pragma unroll
    for(int a=0;a<4;a++)
#pragma unroll
      for(int b=0;b<4;b++){
        float s = ga[a]+gb[b];
        float ws = (s >= 0.f) ? w : w2;
        acc[a][b] = fmaf(s, ws, acc[a][b]);
      }
  }
#pragma unroll
  for(int a=0;a<4;a++)
#pragma unroll
    for(int b=0;b<4;b++){
      int i = i0 + ti*4 + a, j = j0 + tj + 16*b;
      e[((size_t)h*N + i)*N + j] = acc[a][b];
    }
}

// ---------------- K4: per-(h,i) row fusion ----------------
__global__ __launch_bounds__(256) void row_kernel(float* __restrict__ e,
                                                  float* __restrict__ gam,
                                                  const int* __restrict__ adj,
                                                  const float* __restrict__ nf,
                                                  const float* __restrict__ ng,
                                                  float* __restrict__ mgA,
                                                  float* __restrict__ sgA){
  __shared__ float es[1024];
  __shared__ float nfs[1024];
  __shared__ unsigned char adjs[1024];
  __shared__ float scr[4];
  int i = blockIdx.x, h = blockIdx.y, t = threadIdx.x;
  size_t base = ((size_t)h*N + i)*N;
  float ngv = ng[h*N + i];
#pragma unroll
  for(int k=0;k<4;k++){
    int j = t + k*256;
    es[j]  = e[base + j];
    nfs[j] = nf[j];
    adjs[j] = (adj[(size_t)i*N + j] > 0) ? 1 : 0;
  }
  __syncthreads();
  float ml=-FLT_MAX_, mo=-FLT_MAX_, ma=-FLT_MAX_;
#pragma unroll
  for(int k=0;k<4;k++){
    int j = t + k*256;
    float ev = es[j];
    mo = fmaxf(mo, ev);
    if(adjs[j]) ml = fmaxf(ml, ev);
    ma = fmaxf(ma, fabsf(nfs[j]-ngv));
  }
  ml = bred_max(ml, scr); mo = bred_max(mo, scr); ma = bred_max(ma, scr);
  float sl=0.f, so=0.f, sa=0.f;
#pragma unroll
  for(int k=0;k<4;k++){
    int j = t + k*256;
    float ev = es[j];
    so += __expf(ev-mo);
    if(adjs[j]) sl += __expf(ev-ml);
    sa += __expf(fabsf(nfs[j]-ngv)-ma);
  }
  sl = bred_sum(sl, scr); so = bred_sum(so, scr); sa = bred_sum(sa, scr);
  float isl = 1.f/sl, iso = 1.f/so, isa = 1.f/sa;
  float mg = -FLT_MAX_;
  float gloc[4];
#pragma unroll
  for(int k=0;k<4;k++){
    int j = t + k*256;
    float ev = es[j];
    float omega = __expf(ev-mo)*iso;
    float alpha = __expf(fabsf(nfs[j]-ngv)-ma)*isa;
    float g = 0.5f*(omega + 1.f - alpha);
    gloc[k] = g;
    gam[base+j] = g;
    float a1 = adjs[j] ? __expf(ev-ml)*isl : 0.f;
    e[base+j] = a1;
    mg = fmaxf(mg, g);
  }
  mg = bred_max(mg, scr);
  float sg = 0.f;
#pragma unroll
  for(int k=0;k<4;k++) sg += __expf((gloc[k]-mg)/1e-3f);
  sg = bred_sum(sg, scr);
  if(t==0){ mgA[h*N+i]=mg; sgA[h*N+i]=sg; }
}

// ---------------- K5: exact top-512 column select, slab version ----------------
// Block = 32 adjacent columns of one (h, array) slab. Lanes = (rowgroup, col):
// every global load coalesces (32 consecutive floats per rowgroup).
// hist[bucket][col] -> bank = col (<=2-way, free). Radix over 4 bytes;
// kth after last pass = #ties to accept; fast path when all ties accepted.
__device__ __forceinline__ void radix_scan(int (*hist)[32], int (*part)[32],
                                           unsigned* pref, int* kth, int* tietot,
                                           int t, int rg, int col, bool last){
  int ps = 0;
#pragma unroll
  for(int k=0;k<32;k++) ps += hist[rg*32+k][col];
  part[rg][col] = ps;
  __syncthreads();
  if(t < 32){
    int kk = kth[t];
    int acc=0, selc=0, accAt=0; bool found=false;
#pragma unroll
    for(int c=7;c>=0;c--){
      int pc = part[c][t];
      if(!found && acc+pc >= kk){ selc=c; accAt=acc; found=true; }
      acc += pc;
    }
    int a2=accAt, sel=0, newk=1; found=false;
#pragma unroll
    for(int bk=31;bk>=0;bk--){
      int bkt = selc*32+bk;
      int c2 = hist[bkt][t];
      if(!found && a2+c2 >= kk){ sel=bkt; newk=kk-a2; found=true; }
      a2 += c2;
    }
    pref[t] = (pref[t]<<8) | (unsigned)sel;
    kth[t] = newk;
    if(last) tietot[t] = hist[sel][t];
  }
  __syncthreads();
}

__global__ __launch_bounds__(256) void colselect2(const float* __restrict__ a1nd,
                                                  const float* __restrict__ gamv,
                                                  int* __restrict__ mask_l,
                                                  int* __restrict__ mask_g){
  __shared__ int hist[256][32];
  __shared__ int part[8][32];
  __shared__ unsigned pref[32];
  __shared__ int kth[32];
  __shared__ int tietot[32];
  __shared__ int allt_s;
  const float* __restrict__ arr = blockIdx.z ? gamv : a1nd;
  int* __restrict__ mask = blockIdx.z ? mask_g : mask_l;
  int h = blockIdx.y;
  int col0 = blockIdx.x*32;
  int t = threadIdx.x;
  int col = t & 31, rg = t >> 5;
  const float* colbase = arr + ((size_t)h*N)*N + col0 + col;
  if(t < 32){ pref[t] = 0u; kth[t] = KSEL; }
  if(t == 0) allt_s = 1;

  // ---- pass byte 3 (peeled: zero-bucket aggregated per thread) ----
#pragma unroll
  for(int k=0;k<32;k++) hist[k*8+rg][col] = 0;
  __syncthreads();
  {
    int zc = 0;
#pragma unroll 8
    for(int r=0;r<128;r++){
      unsigned u = __float_as_uint(colbase[(size_t)(rg*128+r)*N]);
      if(u == 0u) zc++;
      else atomicAdd(&hist[u>>24][col], 1);
    }
    if(zc) atomicAdd(&hist[0][col], zc);
  }
  __syncthreads();
  radix_scan(hist, part, pref, kth, tietot, t, rg, col, false);

  // ---- passes byte 2..0 ----
#pragma unroll
  for(int b=2;b>=0;b--){
#pragma unroll
    for(int k=0;k<32;k++) hist[k*8+rg][col] = 0;
    __syncthreads();
    unsigned p = pref[col];
    int sh_act = 8*(b+1), sh_bkt = 8*b;
#pragma unroll 8
    for(int r=0;r<128;r++){
      unsigned u = __float_as_uint(colbase[(size_t)(rg*128+r)*N]);
      if((u >> sh_act) == p) atomicAdd(&hist[(u>>sh_bkt)&0xFF][col], 1);
    }
    __syncthreads();
    radix_scan(hist, part, pref, kth, tietot, t, rg, col, b==0);
  }

  unsigned T = pref[col];
  int tneed = kth[col];
  if(t < 32 && kth[t] != tietot[t]) allt_s = 0;
  __syncthreads();

  if(allt_s){
    // all ties accepted -> select u >= T, no ordering needed
#pragma unroll 8
    for(int r=0;r<128;r++){
      int i = rg*128+r;
      unsigned u = __float_as_uint(colbase[(size_t)i*N]);
      if(u >= T) mask[h*N + i] = 1;
    }
  } else {
    // tie-count pass + index-ordered tie selection (lax.top_k semantics)
    int tc = 0;
#pragma unroll 8
    for(int r=0;r<128;r++){
      unsigned u = __float_as_uint(colbase[(size_t)(rg*128+r)*N]);
      tc += (u == T) ? 1 : 0;
    }
    part[rg][col] = tc;
    __syncthreads();
    int run = 0;
#pragma unroll
    for(int c=0;c<8;c++) if(c < rg) run += part[c][col];
#pragma unroll 8
    for(int r=0;r<128;r++){
      int i = rg*128+r;
      unsigned u = __float_as_uint(colbase[(size_t)i*N]);
      bool sel = (u > T) || (u == T && run < tneed);
      run += (u == T) ? 1 : 0;
      if(sel) mask[h*N + i] = 1;
    }
  }
}

// ---------------- K5b: prep P = temp-softmax(gamma) in place ----------------
__global__ __launch_bounds__(256) void prep_p(float* __restrict__ gam,
                                              const float* __restrict__ mgA,
                                              const float* __restrict__ sgA,
                                              const int* __restrict__ mask_g){
  int i = blockIdx.x, h = blockIdx.y, t = threadIdx.x;
  size_t base = ((size_t)h*N + i)*N;
  float mg = mgA[h*N+i];
  float isg = 1.f/sgA[h*N+i];
  int m = mask_g[h*N+i];
  float4* g4 = (float4*)(gam + base);
  float4 v = g4[t];
  if(m){
    v.x = __expf((v.x-mg)/1e-3f)*isg;
    v.y = __expf((v.y-mg)/1e-3f)*isg;
    v.z = __expf((v.z-mg)/1e-3f)*isg;
    v.w = __expf((v.w-mg)/1e-3f)*isg;
  } else {
    const float inv = 1.f/1024.f;
    v = make_float4(inv,inv,inv,inv);
  }
  g4[t] = v;
}

// ---------------- K6: attn_local / attn_global partial matmuls ----------------
__global__ __launch_bounds__(256) void attn_mm(const float* __restrict__ a1nd,
                                               const float* __restrict__ p,
                                               const float* __restrict__ g_r,
                                               float* __restrict__ partL,
                                               float* __restrict__ partG){
  __shared__ __align__(16) float a_t[32][68];
  __shared__ __align__(16) float p_t[32][68];
  __shared__ __align__(16) float b_s[32][68];
  int i0 = blockIdx.x*64, h = blockIdx.y, s = blockIdx.z, j0 = s*128;
  int t = threadIdx.x;
  int fq = t & 15, iq = t >> 4;
  float4 accL[4], accG[4];
#pragma unroll
  for(int r=0;r<4;r++){ accL[r]=make_float4(0,0,0,0); accG[r]=make_float4(0,0,0,0); }
  size_t abase = ((size_t)h*N + i0)*N;
  for(int sub=0; sub<4; sub++){
    int jb = j0 + sub*32;
#pragma unroll
    for(int k=0;k<2;k++){
      int idx = t + k*256;
      int row = idx>>3, c4 = idx&7;
      float4 va = *(const float4*)(a1nd + abase + (size_t)row*N + jb + c4*4);
      float4 vp = *(const float4*)(p    + abase + (size_t)row*N + jb + c4*4);
      a_t[c4*4+0][row]=va.x; a_t[c4*4+1][row]=va.y; a_t[c4*4+2][row]=va.z; a_t[c4*4+3][row]=va.w;
      p_t[c4*4+0][row]=vp.x; p_t[c4*4+1][row]=vp.y; p_t[c4*4+2][row]=vp.z; p_t[c4*4+3][row]=vp.w;
      int rj = idx>>4, d4 = idx&15;
      *(float4*)&b_s[rj][d4*4] = *(const float4*)(g_r + (size_t)(jb+rj)*256 + h*64 + d4*4);
    }
    __syncthreads();
#pragma unroll 4
    for(int j=0;j<32;j++){
      float4 bv = *(float4*)&b_s[j][fq*4];
      float4 av = *(float4*)&a_t[j][iq*4];
      float4 pv = *(float4*)&p_t[j][iq*4];
      accL[0].x = fmaf(av.x, bv.x, accL[0].x); accL[0].y = fmaf(av.x, bv.y, accL[0].y);
      accL[0].z = fmaf(av.x, bv.z, accL[0].z); accL[0].w = fmaf(av.x, bv.w, accL[0].w);
      accL[1].x = fmaf(av.y, bv.x, accL[1].x); accL[1].y = fmaf(av.y, bv.y, accL[1].y);
      accL[1].z = fmaf(av.y, bv.z, accL[1].z); accL[1].w = fmaf(av.y, bv.w, accL[1].w);
      accL[2].x = fmaf(av.z, bv.x, accL[2].x); accL[2].y = fmaf(av.z, bv.y, accL[2].y);
      accL[2].z = fmaf(av.z, bv.z, accL[2].z); accL[2].w = fmaf(av.z, bv.w, accL[2].w);
      accL[3].x = fmaf(av.w, bv.x, accL[3].x); accL[3].y = fmaf(av.w, bv.y, accL[3].y);
      accL[3].z = fmaf(av.w, bv.z, accL[3].z); accL[3].w = fmaf(av.w, bv.w, accL[3].w);
      accG[0].x = fmaf(pv.x, bv.x, accG[0].x); accG[0].y = fmaf(pv.x, bv.y, accG[0].y);
      accG[0].z = fmaf(pv.x, bv.z, accG[0].z); accG[0].w = fmaf(pv.x, bv.w, accG[0].w);
      accG[1].x = fmaf(pv.y, bv.x, accG[1].x); accG[1].y = fmaf(pv.y, bv.y, accG[1].y);
      accG[1].z = fmaf(pv.y, bv.z, accG[1].z); accG[1].w = fmaf(pv.y, bv.w, accG[1].w);
      accG[2].x = fmaf(pv.z, bv.x, accG[2].x); accG[2].y = fmaf(pv.z, bv.y, accG[2].y);
      accG[2].z = fmaf(pv.z, bv.z, accG[2].z); accG[2].w = fmaf(pv.z, bv.w, accG[2].w);
      accG[3].x = fmaf(pv.w, bv.x, accG[3].x); accG[3].y = fmaf(pv.w, bv.y, accG[3].y);
      accG[3].z = fmaf(pv.w, bv.z, accG[3].z); accG[3].w = fmaf(pv.w, bv.w, accG[3].w);
    }
    __syncthreads();
  }
#pragma unroll
  for(int r=0;r<4;r++){
    int i = i0 + iq*4 + r;
    size_t o = ((size_t)s*N + i)*256 + h*64 + fq*4;
    *(float4*)&partL[o] = accL[r];
    *(float4*)&partG[o] = accG[r];
  }
}

// ---------------- K7: reduce partials + delta-gate epilogue ----------------
__global__ __launch_bounds__(256) void epilogue(const float* __restrict__ partL,
                                                const float* __restrict__ partG,
                                                const int* __restrict__ mask_l,
                                                const float* __restrict__ W_delta,
                                                const float* __restrict__ b_delta,
                                                float* __restrict__ out){
  __shared__ float cat[4][128];
  __shared__ float inter_s[4][64];
  int i = blockIdx.x, t = threadIdx.x;
  int h = t>>6, f = t&63;
  float sl = 0.f, sg = 0.f;
#pragma unroll
  for(int s2=0;s2<8;s2++){
    size_t o = ((size_t)s2*N + i)*256 + h*64 + f;
    sl += partL[o];
    sg += partG[o];
  }
  if(!mask_l[h*N + i]) sl = 0.f;
  cat[h][f]      = sl;
  cat[h][64 + f] = sg;
  __syncthreads();
  float d = b_delta[f];
  for(int c=0;c<128;c++) d = fmaf(cat[h][c], W_delta[(size_t)c*64 + f], d);
  d = (d >= 0.f) ? d : 0.2f*d;
  inter_s[h][f] = d;
  __syncthreads();
  float m = inter_s[0][f];
#pragma unroll
  for(int hh=1;hh<4;hh++) m = fmaxf(m, inter_s[hh][f]);
  float ssum = 0.f;
#pragma unroll
  for(int hh=0;hh<4;hh++) ssum += __expf(inter_s[hh][f]-m);
  float delta = __expf(d - m)/ssum;
  out[(size_t)i*256 + h*64 + f] = delta*sl + (1.f - delta)*sg;
}

// ---------------- launch ----------------
extern "C" void kernel_launch(void* const* d_in, const int* in_sizes, int n_in,
                              void* d_out, int out_size, void* d_ws, size_t ws_size,
                              hipStream_t stream) {
  const float* feats  = (const float*)d_in[0];
  const float* x      = (const float*)d_in[1];
  const int*   adj    = (const int*)  d_in[2];
  const float* W_l    = (const float*)d_in[3];
  const float* W_r    = (const float*)d_in[4];
  const float* attn_w = (const float*)d_in[5];
  const float* W_delta= (const float*)d_in[6];
  const float* b_delta= (const float*)d_in[7];
  float* out = (float*)d_out;

  float* ws = (float*)d_ws;
  size_t off = 0;
  float* g_l   = ws+off; off += (size_t)N*256;
  float* g_r   = ws+off; off += (size_t)N*256;
  float* e     = ws+off; off += (size_t)HN*N*N;      // becomes a_1nd
  float* gam   = ws+off; off += (size_t)HN*N*N;      // becomes P after prep_p
  float* partL = ws+off; off += (size_t)8*N*256;
  float* partG = ws+off; off += (size_t)8*N*256;
  float* pmin_f= ws+off; off += 16*128;
  float* pmax_f= ws+off; off += 16*128;
  float* pmin_g= ws+off; off += 16*256;
  float* pmax_g= ws+off; off += 16*256;
  float* fmn   = ws+off; off += 128;
  float* fmx   = ws+off; off += 128;
  float* gmn   = ws+off; off += 256;
  float* gmx   = ws+off; off += 256;
  float* nf    = ws+off; off += N;
  float* ng    = ws+off; off += (size_t)HN*N;
  float* mgA   = ws+off; off += (size_t)HN*N;
  float* sgA   = ws+off; off += (size_t)HN*N;
  int* mask_l  = (int*)(ws+off); off += (size_t)HN*N;
  int* mask_g  = (int*)(ws+off); off += (size_t)HN*N;

  zero_ints<<<32, 256, 0, stream>>>(mask_l, 2*HN*N);

  gemm_lr<<<dim3(256,2), 256, 0, stream>>>(x, W_l, W_r, g_l, g_r);

  colmm_part<<<dim3(16,2), 256, 0, stream>>>(feats, g_r, pmin_f, pmax_f, pmin_g, pmax_g);
  colmm_fin <<<dim3(2),    256, 0, stream>>>(pmin_f, pmax_f, pmin_g, pmax_g, fmn, fmx, gmn, gmx);
  norms_kernel<<<dim3(N,2),256, 0, stream>>>(feats, g_r, fmn, fmx, gmn, gmx, nf, ng);

  compute_e<<<dim3(16,16,HN), 256, 0, stream>>>(g_l, g_r, attn_w, e);

  row_kernel<<<dim3(N,HN), 256, 0, stream>>>(e, gam, adj, nf, ng, mgA, sgA);

  colselect2<<<dim3(N/32, HN, 2), 256, 0, stream>>>(e, gam, mask_l, mask_g);

  prep_p<<<dim3(N,HN), 256, 0, stream>>>(gam, mgA, sgA, mask_g);

  attn_mm<<<dim3(16,HN,8), 256, 0, stream>>>(e, gam, g_r, partL, partG);

  epilogue<<<N, 256, 0, stream>>>(partL, partG, mask_l, W_delta, b_delta, out);
}

// Round 5
// 229.565 us; speedup vs baseline: 1.3091x; 1.3091x over previous
//
#include <hip/hip_runtime.h>
#include <cstdint>
#include <cstddef>

#define N 1024
#define HN 4
#define FDIM 64
#define KSEL 512
#define FLT_MAX_ 3.402823466e+38f

// ---------------- reduction helpers (blockDim.x == 256) ----------------
__device__ __forceinline__ float wred_sum(float v){
#pragma unroll
  for(int o=32;o>0;o>>=1) v += __shfl_down(v,o,64);
  return v;
}
__device__ __forceinline__ float wred_max(float v){
#pragma unroll
  for(int o=32;o>0;o>>=1) v = fmaxf(v,__shfl_down(v,o,64));
  return v;
}
__device__ __forceinline__ float bred_sum(float v, float* scr){
  int t=threadIdx.x;
  v = wred_sum(v);
  __syncthreads();
  if((t&63)==0) scr[t>>6]=v;
  __syncthreads();
  return (scr[0]+scr[1])+(scr[2]+scr[3]);
}
__device__ __forceinline__ float bred_max(float v, float* scr){
  int t=threadIdx.x;
  v = wred_max(v);
  __syncthreads();
  if((t&63)==0) scr[t>>6]=v;
  __syncthreads();
  return fmaxf(fmaxf(scr[0],scr[1]),fmaxf(scr[2],scr[3]));
}

// ---------------- K0: zero masks ----------------
__global__ __launch_bounds__(256) void zero_ints(int* p, int n){
  int i = blockIdx.x*256 + threadIdx.x;
  if(i<n) p[i]=0;
}

// ---------------- K1: g = x@W ----------------
__global__ __launch_bounds__(256) void gemm_lr(const float* __restrict__ x,
                                               const float* __restrict__ W_l,
                                               const float* __restrict__ W_r,
                                               float* __restrict__ g_l,
                                               float* __restrict__ g_r){
  int i0 = blockIdx.x*4, t = threadIdx.x;
  const float* __restrict__ W = blockIdx.y ? W_r : W_l;
  float* __restrict__ g = blockIdx.y ? g_r : g_l;
  float acc[4] = {0.f,0.f,0.f,0.f};
#pragma unroll 8
  for(int k=0;k<256;k++){
    float w = W[(size_t)k*256 + t];
#pragma unroll
    for(int r=0;r<4;r++) acc[r] = fmaf(x[(size_t)(i0+r)*256 + k], w, acc[r]);
  }
#pragma unroll
  for(int r=0;r<4;r++) g[(size_t)(i0+r)*256 + t] = acc[r];
}

// ---------------- K2p/K2f/K2n: min/max + norms ----------------
__global__ __launch_bounds__(256) void colmm_part(const float* __restrict__ feats,
                                                  const float* __restrict__ g_r,
                                                  float* __restrict__ pmin_f, float* __restrict__ pmax_f,
                                                  float* __restrict__ pmin_g, float* __restrict__ pmax_g){
  int chunk = blockIdx.x, src = blockIdx.y, t = threadIdx.x;
  int cols = src ? 256 : 128;
  const float* in = src ? g_r : feats;
  if(t < cols){
    float lo = FLT_MAX_, hi = -FLT_MAX_;
    int r0 = chunk*64;
    for(int r=0;r<64;r++){
      float v = in[(size_t)(r0+r)*cols + t];
      lo = fminf(lo,v); hi = fmaxf(hi,v);
    }
    if(src){ pmin_g[chunk*256+t]=lo; pmax_g[chunk*256+t]=hi; }
    else   { pmin_f[chunk*128+t]=lo; pmax_f[chunk*128+t]=hi; }
  }
}

__global__ __launch_bounds__(256) void colmm_fin(const float* __restrict__ pmin_f, const float* __restrict__ pmax_f,
                                                 const float* __restrict__ pmin_g, const float* __restrict__ pmax_g,
                                                 float* __restrict__ fmn, float* __restrict__ fmx,
                                                 float* __restrict__ gmn, float* __restrict__ gmx){
  int src = blockIdx.x, t = threadIdx.x;
  int cols = src ? 256 : 128;
  if(t < cols){
    float lo = FLT_MAX_, hi = -FLT_MAX_;
    const float* pn = src ? pmin_g : pmin_f;
    const float* px = src ? pmax_g : pmax_f;
    for(int k=0;k<16;k++){
      lo = fminf(lo, pn[k*cols+t]);
      hi = fmaxf(hi, px[k*cols+t]);
    }
    if(src){ gmn[t]=lo; gmx[t]=hi; } else { fmn[t]=lo; fmx[t]=hi; }
  }
}

__global__ __launch_bounds__(256) void norms_kernel(const float* __restrict__ feats,
                                                    const float* __restrict__ g_r,
                                                    const float* __restrict__ fmn, const float* __restrict__ fmx,
                                                    const float* __restrict__ gmn, const float* __restrict__ gmx,
                                                    float* __restrict__ nf, float* __restrict__ ng){
  __shared__ float scr[4];
  int i = blockIdx.x, z = blockIdx.y, t = threadIdx.x;
  if(z==0){
    float u = 0.f;
    if(t < 128){
      float d = fmx[t]-fmn[t];
      float v = feats[(size_t)i*128 + t];
      u = (d==0.f) ? 0.f : (v - fmn[t])/d;
    }
    float tot = bred_sum(u*u, scr);
    if(t==0) nf[i] = sqrtf(tot);
  } else {
    int c = t, hh = t>>6;
    float d = gmx[c]-gmn[c];
    float v = g_r[(size_t)i*256 + c];
    float u = (v - gmn[c])/d;
    float ss = wred_sum(u*u);
    if((t&63)==0) ng[hh*N + i] = sqrtf(ss);
  }
}

// ---------------- K3: e[h][i][j] ----------------
__global__ __launch_bounds__(256) void compute_e(const float* __restrict__ g_l,
                                                 const float* __restrict__ g_r,
                                                 const float* __restrict__ attn_w,
                                                 float* __restrict__ e){
  __shared__ float grs[64][65];
  __shared__ float gls[64][65];
  __shared__ float aw[64], aw2[64];
  int h = blockIdx.z, i0 = blockIdx.y*64, j0 = blockIdx.x*64;
  int t = threadIdx.x;
  if(t < 64){ float w = attn_w[t]; aw[t]=w; aw2[t]=0.2f*w; }
#pragma unroll
  for(int k=0;k<16;k++){
    int idx = t + k*256; int r = idx>>6, f = idx&63;
    grs[r][f] = g_r[(size_t)(i0+r)*256 + h*64 + f];
    gls[r][f] = g_l[(size_t)(j0+r)*256 + h*64 + f];
  }
  __syncthreads();
  int tj = t&15, ti = t>>4;
  float acc[4][4];
#pragma unroll
  for(int a=0;a<4;a++)
#pragma unroll
    for(int b=0;b<4;b++) acc[a][b]=0.f;
  for(int f=0;f<64;f++){
    float w = aw[f], w2 = aw2[f];
    float ga[4], gb[4];
#pragma unroll
    for(int a=0;a<4;a++) ga[a] = grs[ti*4+a][f];
#pragma unroll
    for(int b=0;b<4;b++) gb[b] = gls[tj+16*b][f];
#pragma unroll
    for(int a=0;a<4;a++)
#pragma unroll
      for(int b=0;b<4;b++){
        float s = ga[a]+gb[b];
        float ws = (s >= 0.f) ? w : w2;
        acc[a][b] = fmaf(s, ws, acc[a][b]);
      }
  }
#pragma unroll
  for(int a=0;a<4;a++)
#pragma unroll
    for(int b=0;b<4;b++){
      int i = i0 + ti*4 + a, j = j0 + tj + 16*b;
      e[((size_t)h*N + i)*N + j] = acc[a][b];
    }
}

// ---------------- K4: per-(h,i) row stats (reductions only) ----------------
__global__ __launch_bounds__(256) void row_stats(const float* __restrict__ e,
                                                 const int* __restrict__ adj,
                                                 const float* __restrict__ nf,
                                                 const float* __restrict__ ng,
                                                 float* __restrict__ mlA, float* __restrict__ islA,
                                                 float* __restrict__ moA, float* __restrict__ isoA,
                                                 float* __restrict__ maA, float* __restrict__ isaA,
                                                 float* __restrict__ mgA, float* __restrict__ sgA){
  __shared__ float es[1024];
  __shared__ float nfs[1024];
  __shared__ unsigned char adjs[1024];
  __shared__ float scr[4];
  int i = blockIdx.x, h = blockIdx.y, t = threadIdx.x;
  size_t base = ((size_t)h*N + i)*N;
  float ngv = ng[h*N + i];
#pragma unroll
  for(int k=0;k<4;k++){
    int j = t + k*256;
    es[j]  = e[base + j];
    nfs[j] = nf[j];
    adjs[j] = (adj[(size_t)i*N + j] > 0) ? 1 : 0;
  }
  __syncthreads();
  float ml=-FLT_MAX_, mo=-FLT_MAX_, ma=-FLT_MAX_;
#pragma unroll
  for(int k=0;k<4;k++){
    int j = t + k*256;
    float ev = es[j];
    mo = fmaxf(mo, ev);
    if(adjs[j]) ml = fmaxf(ml, ev);
    ma = fmaxf(ma, fabsf(nfs[j]-ngv));
  }
  ml = bred_max(ml, scr); mo = bred_max(mo, scr); ma = bred_max(ma, scr);
  float sl=0.f, so=0.f, sa=0.f;
#pragma unroll
  for(int k=0;k<4;k++){
    int j = t + k*256;
    float ev = es[j];
    so += __expf(ev-mo);
    if(adjs[j]) sl += __expf(ev-ml);
    sa += __expf(fabsf(nfs[j]-ngv)-ma);
  }
  sl = bred_sum(sl, scr); so = bred_sum(so, scr); sa = bred_sum(sa, scr);
  float isl = 1.f/sl, iso = 1.f/so, isa = 1.f/sa;
  float mg = -FLT_MAX_;
  float gloc[4];
#pragma unroll
  for(int k=0;k<4;k++){
    int j = t + k*256;
    float ev = es[j];
    float omega = __expf(ev-mo)*iso;
    float alpha = __expf(fabsf(nfs[j]-ngv)-ma)*isa;
    float g = 0.5f*(omega + 1.f - alpha);
    gloc[k] = g;
    mg = fmaxf(mg, g);
  }
  mg = bred_max(mg, scr);
  float sg = 0.f;
#pragma unroll
  for(int k=0;k<4;k++) sg += __expf((gloc[k]-mg)/1e-3f);
  sg = bred_sum(sg, scr);
  if(t==0){
    mlA[h*N+i]=ml; islA[h*N+i]=isl;
    moA[h*N+i]=mo; isoA[h*N+i]=iso;
    maA[h*N+i]=ma; isaA[h*N+i]=isa;
    mgA[h*N+i]=mg; sgA[h*N+i]=sg;
  }
}

// ---------------- K4b: applyT — elementwise a_1nd/gamma + transpose ----------------
// grid (136, HN): pairwise 64x64 tile transpose. e -> a1T in place; gamT written.
__global__ __launch_bounds__(256) void applyT(float* __restrict__ e,
                                              float* __restrict__ gamT,
                                              const int* __restrict__ adj,
                                              const float* __restrict__ nf,
                                              const float* __restrict__ mlA, const float* __restrict__ islA,
                                              const float* __restrict__ moA, const float* __restrict__ isoA,
                                              const float* __restrict__ maA, const float* __restrict__ isaA,
                                              const float* __restrict__ ng){
  __shared__ __align__(16) float buf1[64][65];   // gamma staging
  __shared__ __align__(16) float buf2[64][65];   // a1 of tile1
  __shared__ __align__(16) float buf3[64][65];   // a1 of tile2
  __shared__ float rml[64], risl[64], rmo[64], riso[64], rma[64], risa[64], rng[64], nfs[64];
  int h = blockIdx.y;
  int pp = blockIdx.x; int a = 0;
  while(pp >= 16 - a){ pp -= 16 - a; a++; }
  int b = a + pp;                 // a <= b
  int t = threadIdx.x;
  int rg = t >> 4, c4 = t & 15;

  // ---- phase 1: tile (a,b) ----
  int i0 = a*64, j0 = b*64;
  if(t < 64){
    int o = h*N + i0 + t;
    rml[t]=mlA[o]; risl[t]=islA[o]; rmo[t]=moA[o]; riso[t]=isoA[o];
    rma[t]=maA[o]; risa[t]=isaA[o]; rng[t]=ng[o]; nfs[t]=nf[j0+t];
  }
  __syncthreads();
  float4 ev[4]; int4 av[4];
#pragma unroll
  for(int k=0;k<4;k++){
    int row = rg*4+k;
    ev[k] = *(const float4*)(e + ((size_t)h*N + i0+row)*N + j0 + c4*4);
    av[k] = *(const int4*)(adj + (size_t)(i0+row)*N + j0 + c4*4);
  }
#pragma unroll
  for(int k=0;k<4;k++){
    int row = rg*4+k;
    float ml=rml[row], isl=risl[row], mo=rmo[row], iso=riso[row];
    float ma=rma[row], isa=risa[row], ngv=rng[row];
    float evc[4] = {ev[k].x,ev[k].y,ev[k].z,ev[k].w};
    int   avc[4] = {av[k].x,av[k].y,av[k].z,av[k].w};
#pragma unroll
    for(int c=0;c<4;c++){
      int j = c4*4+c;
      buf2[j][row] = (avc[c]>0) ? __expf(evc[c]-ml)*isl : 0.f;
      float omega = __expf(evc[c]-mo)*iso;
      float alpha = __expf(fabsf(nfs[j]-ngv)-ma)*isa;
      buf1[j][row] = 0.5f*(omega + 1.f - alpha);
    }
  }
  __syncthreads();
  // write gamma tile1 transposed -> gamT tile (b,a)
#pragma unroll
  for(int k=0;k<4;k++){
    int jr = rg*4+k;
    *(float4*)(gamT + ((size_t)h*N + j0+jr)*N + i0 + c4*4) = *(float4*)&buf1[jr][c4*4];
  }
  if(a == b){
    // a1 tile -> e(a,a); all loads of e(a,a) completed before the sync above
#pragma unroll
    for(int k=0;k<4;k++){
      int jr = rg*4+k;
      *(float4*)(e + ((size_t)h*N + j0+jr)*N + i0 + c4*4) = *(float4*)&buf2[jr][c4*4];
    }
    return;
  }
  // ---- phase 2: tile (b,a) ----
  int i1 = b*64, j1 = a*64;
  __syncthreads();           // gamT(b,a) writes (buf1 readers) done before buf1 reuse
  if(t < 64){
    int o = h*N + i1 + t;
    rml[t]=mlA[o]; risl[t]=islA[o]; rmo[t]=moA[o]; riso[t]=isoA[o];
    rma[t]=maA[o]; risa[t]=isaA[o]; rng[t]=ng[o]; nfs[t]=nf[j1+t];
  }
#pragma unroll
  for(int k=0;k<4;k++){
    int row = rg*4+k;
    ev[k] = *(const float4*)(e + ((size_t)h*N + i1+row)*N + j1 + c4*4);
    av[k] = *(const int4*)(adj + (size_t)(i1+row)*N + j1 + c4*4);
  }
  __syncthreads();           // all e(b,a) reads done + stats staged
  // a1 tile1 (buf2) -> e tile (b,a)
#pragma unroll
  for(int k=0;k<4;k++){
    int jr = rg*4+k;
    *(float4*)(e + ((size_t)h*N + i1+jr)*N + j1 + c4*4) = *(float4*)&buf2[jr][c4*4];
  }
#pragma unroll
  for(int k=0;k<4;k++){
    int row = rg*4+k;
    float ml=rml[row], isl=risl[row], mo=rmo[row], iso=riso[row];
    float ma=rma[row], isa=risa[row], ngv=rng[row];
    float evc[4] = {ev[k].x,ev[k].y,ev[k].z,ev[k].w};
    int   avc[4] = {av[k].x,av[k].y,av[k].z,av[k].w};
#pragma unroll
    for(int c=0;c<4;c++){
      int j = c4*4+c;
      buf3[j][row] = (avc[c]>0) ? __expf(evc[c]-ml)*isl : 0.f;
      float omega = __expf(evc[c]-mo)*iso;
      float alpha = __expf(fabsf(nfs[j]-ngv)-ma)*isa;
      buf1[j][row] = 0.5f*(omega + 1.f - alpha);
    }
  }
  __syncthreads();
#pragma unroll
  for(int k=0;k<4;k++){
    int jr = rg*4+k;
    *(float4*)(gamT + ((size_t)h*N + j1+jr)*N + i1 + c4*4) = *(float4*)&buf1[jr][c4*4];
    *(float4*)(e    + ((size_t)h*N + j1+jr)*N + i1 + c4*4) = *(float4*)&buf3[jr][c4*4];
  }
}

// ---------------- K5: exact top-512 select on contiguous columns ----------------
// grid (N, HN, 2). src row (h*N+j) of transposed array = original column j.
__global__ __launch_bounds__(256) void colselect3(const float* __restrict__ a1T,
                                                  const float* __restrict__ gaT,
                                                  int* __restrict__ mask_l,
                                                  int* __restrict__ mask_g){
  __shared__ __align__(16) unsigned vals[1024];
  __shared__ __align__(16) int hist4[4][256];
  __shared__ int wtot[4];
  __shared__ int bsel_s, knew_s, tiet_s;
  int j = blockIdx.x, h = blockIdx.y;
  const float* __restrict__ src = (blockIdx.z ? gaT : a1T) + ((size_t)h*N + j)*N;
  int* __restrict__ mask = blockIdx.z ? mask_g : mask_l;
  int t = threadIdx.x, lane = t&63, w = t>>6;
  uint4 u4 = ((const uint4*)src)[t];
  *(uint4*)&vals[4*t] = u4;
  unsigned ur[4] = {u4.x, u4.y, u4.z, u4.w};
  unsigned prefix = 0; int kth = KSEL;
  __syncthreads();
#pragma unroll
  for(int b=3;b>=0;b--){
    *(int4*)&((int*)hist4)[4*t] = make_int4(0,0,0,0);
    __syncthreads();
    int* hw = hist4[w];
#pragma unroll
    for(int q=0;q<4;q++){
      unsigned u = (b==3) ? ur[q] : vals[t + 256*q];
      int bucket = (u >> (8*b)) & 0xFF;
      bool act = (b==3) || ((u >> (8*(b+1))) == prefix);
      if(act){
        int lead = __ffsll((unsigned long long)__ballot(true)) - 1;
        int maj = __shfl(bucket, lead, 64);
        if(bucket == maj){
          int cnt = (int)__popcll(__ballot(true));
          if(lane == lead) atomicAdd(&hw[maj], cnt);
        } else {
          atomicAdd(&hw[bucket], 1);
        }
      }
    }
    __syncthreads();
    int u255 = 255 - t;
    int hv = hist4[0][u255]+hist4[1][u255]+hist4[2][u255]+hist4[3][u255];
    int p = hv;
#pragma unroll
    for(int off=1; off<64; off<<=1){
      int q2 = __shfl_up(p, off, 64);
      if(lane >= off) p += q2;
    }
    if(lane==63) wtot[w] = p;
    __syncthreads();
    int add = 0;
#pragma unroll
    for(int ww=0;ww<4;ww++) if(ww < w) add += wtot[ww];
    int ge = p + add, ge1 = ge - hv;
    if(ge >= kth && ge1 < kth){
      bsel_s = u255; knew_s = kth - ge1;
      if(b==0) tiet_s = hv;
    }
    __syncthreads();
    prefix = (prefix << 8) | (unsigned)bsel_s;
    kth = knew_s;
    __syncthreads();
  }
  unsigned T = prefix;
  int tneed = kth;
  if(tiet_s == tneed){
    // all ties accepted -> plain threshold
#pragma unroll
    for(int q=0;q<4;q++)
      if(ur[q] >= T) mask[h*N + 4*t + q] = 1;
  } else {
    int tc = 0;
#pragma unroll
    for(int q=0;q<4;q++) tc += (ur[q]==T) ? 1 : 0;
    int pc = tc;
#pragma unroll
    for(int off=1; off<64; off<<=1){
      int q2 = __shfl_up(pc, off, 64);
      if(lane >= off) pc += q2;
    }
    if(lane==63) wtot[w] = pc;
    __syncthreads();
    int add = 0;
#pragma unroll
    for(int ww=0;ww<4;ww++) if(ww < w) add += wtot[ww];
    pc += add;
    int run = pc - tc;          // ties at indices < 4t
#pragma unroll
    for(int q=0;q<4;q++){
      unsigned u = ur[q];
      bool sel = (u > T) || (u == T && run < tneed);
      run += (u == T) ? 1 : 0;
      if(sel) mask[h*N + 4*t + q] = 1;
    }
  }
}

// ---------------- K6: attn matmuls, transposed inputs + inline P transform ----------------
// grid (16, HN, 8): x = i-tile (64), y = h, z = j-split (128 cols)
__global__ __launch_bounds__(256) void attn_mm(const float* __restrict__ a1T,
                                               const float* __restrict__ gaT,
                                               const float* __restrict__ g_r,
                                               const float* __restrict__ mgA,
                                               const float* __restrict__ sgA,
                                               const int* __restrict__ mask_g,
                                               float* __restrict__ partL,
                                               float* __restrict__ partG){
  __shared__ __align__(16) float a_t[32][68];
  __shared__ __align__(16) float p_t[32][68];
  __shared__ __align__(16) float b_s[32][68];
  __shared__ float mgv[64], isgv[64];
  __shared__ int mgf[64];
  int i0 = blockIdx.x*64, h = blockIdx.y, s = blockIdx.z, j0 = s*128;
  int t = threadIdx.x;
  if(t < 64){
    mgv[t]  = mgA[h*N + i0 + t];
    isgv[t] = 1.f / sgA[h*N + i0 + t];
    mgf[t]  = mask_g[h*N + i0 + t];
  }
  __syncthreads();
  int fq = t & 15, iq = t >> 4;
  float4 accL[4], accG[4];
#pragma unroll
  for(int r=0;r<4;r++){ accL[r]=make_float4(0,0,0,0); accG[r]=make_float4(0,0,0,0); }
  for(int sub=0; sub<4; sub++){
    int jb = j0 + sub*32;
#pragma unroll
    for(int k=0;k<2;k++){
      int idx = t + k*256;
      int jj = idx>>4, i4 = idx&15;
      size_t base = ((size_t)h*N + jb + jj)*N + i0 + i4*4;
      *(float4*)&a_t[jj][i4*4] = *(const float4*)(a1T + base);
      float4 g4 = *(const float4*)(gaT + base);
      int ii = i4*4;
      const float inv = 1.f/1024.f;
      float4 p4;
      p4.x = mgf[ii+0] ? __expf((g4.x - mgv[ii+0])/1e-3f)*isgv[ii+0] : inv;
      p4.y = mgf[ii+1] ? __expf((g4.y - mgv[ii+1])/1e-3f)*isgv[ii+1] : inv;
      p4.z = mgf[ii+2] ? __expf((g4.z - mgv[ii+2])/1e-3f)*isgv[ii+2] : inv;
      p4.w = mgf[ii+3] ? __expf((g4.w - mgv[ii+3])/1e-3f)*isgv[ii+3] : inv;
      *(float4*)&p_t[jj][i4*4] = p4;
      *(float4*)&b_s[jj][i4*4] = *(const float4*)(g_r + (size_t)(jb+jj)*256 + h*64 + i4*4);
    }
    __syncthreads();
#pragma unroll 4
    for(int j=0;j<32;j++){
      float4 bv = *(float4*)&b_s[j][fq*4];
      float4 av = *(float4*)&a_t[j][iq*4];
      float4 pv = *(float4*)&p_t[j][iq*4];
      accL[0].x = fmaf(av.x, bv.x, accL[0].x); accL[0].y = fmaf(av.x, bv.y, accL[0].y);
      accL[0].z = fmaf(av.x, bv.z, accL[0].z); accL[0].w = fmaf(av.x, bv.w, accL[0].w);
      accL[1].x = fmaf(av.y, bv.x, accL[1].x); accL[1].y = fmaf(av.y, bv.y, accL[1].y);
      accL[1].z = fmaf(av.y, bv.z, accL[1].z); accL[1].w = fmaf(av.y, bv.w, accL[1].w);
      accL[2].x = fmaf(av.z, bv.x, accL[2].x); accL[2].y = fmaf(av.z, bv.y, accL[2].y);
      accL[2].z = fmaf(av.z, bv.z, accL[2].z); accL[2].w = fmaf(av.z, bv.w, accL[2].w);
      accL[3].x = fmaf(av.w, bv.x, accL[3].x); accL[3].y = fmaf(av.w, bv.y, accL[3].y);
      accL[3].z = fmaf(av.w, bv.z, accL[3].z); accL[3].w = fmaf(av.w, bv.w, accL[3].w);
      accG[0].x = fmaf(pv.x, bv.x, accG[0].x); accG[0].y = fmaf(pv.x, bv.y, accG[0].y);
      accG[0].z = fmaf(pv.x, bv.z, accG[0].z); accG[0].w = fmaf(pv.x, bv.w, accG[0].w);
      accG[1].x = fmaf(pv.y, bv.x, accG[1].x); accG[1].y = fmaf(pv.y, bv.y, accG[1].y);
      accG[1].z = fmaf(pv.y, bv.z, accG[1].z); accG[1].w = fmaf(pv.y, bv.w, accG[1].w);
      accG[2].x = fmaf(pv.z, bv.x, accG[2].x); accG[2].y = fmaf(pv.z, bv.y, accG[2].y);
      accG[2].z = fmaf(pv.z, bv.z, accG[2].z); accG[2].w = fmaf(pv.z, bv.w, accG[2].w);
      accG[3].x = fmaf(pv.w, bv.x, accG[3].x); accG[3].y = fmaf(pv.w, bv.y, accG[3].y);
      accG[3].z = fmaf(pv.w, bv.z, accG[3].z); accG[3].w = fmaf(pv.w, bv.w, accG[3].w);
    }
    __syncthreads();
  }
#pragma unroll
  for(int r=0;r<4;r++){
    int i = i0 + iq*4 + r;
    size_t o = ((size_t)s*N + i)*256 + h*64 + fq*4;
    *(float4*)&partL[o] = accL[r];
    *(float4*)&partG[o] = accG[r];
  }
}

// ---------------- K7: reduce partials + delta-gate epilogue ----------------
__global__ __launch_bounds__(256) void epilogue(const float* __restrict__ partL,
                                                const float* __restrict__ partG,
                                                const int* __restrict__ mask_l,
                                                const float* __restrict__ W_delta,
                                                const float* __restrict__ b_delta,
                                                float* __restrict__ out){
  __shared__ float cat[4][128];
  __shared__ float inter_s[4][64];
  int i = blockIdx.x, t = threadIdx.x;
  int h = t>>6, f = t&63;
  float sl = 0.f, sg = 0.f;
#pragma unroll
  for(int s2=0;s2<8;s2++){
    size_t o = ((size_t)s2*N + i)*256 + h*64 + f;
    sl += partL[o];
    sg += partG[o];
  }
  if(!mask_l[h*N + i]) sl = 0.f;
  cat[h][f]      = sl;
  cat[h][64 + f] = sg;
  __syncthreads();
  float d = b_delta[f];
  for(int c=0;c<128;c++) d = fmaf(cat[h][c], W_delta[(size_t)c*64 + f], d);
  d = (d >= 0.f) ? d : 0.2f*d;
  inter_s[h][f] = d;
  __syncthreads();
  float m = inter_s[0][f];
#pragma unroll
  for(int hh=1;hh<4;hh++) m = fmaxf(m, inter_s[hh][f]);
  float ssum = 0.f;
#pragma unroll
  for(int hh=0;hh<4;hh++) ssum += __expf(inter_s[hh][f]-m);
  float delta = __expf(d - m)/ssum;
  out[(size_t)i*256 + h*64 + f] = delta*sl + (1.f - delta)*sg;
}

// ---------------- launch ----------------
extern "C" void kernel_launch(void* const* d_in, const int* in_sizes, int n_in,
                              void* d_out, int out_size, void* d_ws, size_t ws_size,
                              hipStream_t stream) {
  const float* feats  = (const float*)d_in[0];
  const float* x      = (const float*)d_in[1];
  const int*   adj    = (const int*)  d_in[2];
  const float* W_l    = (const float*)d_in[3];
  const float* W_r    = (const float*)d_in[4];
  const float* attn_w = (const float*)d_in[5];
  const float* W_delta= (const float*)d_in[6];
  const float* b_delta= (const float*)d_in[7];
  float* out = (float*)d_out;

  float* ws = (float*)d_ws;
  size_t off = 0;
  float* g_l   = ws+off; off += (size_t)N*256;
  float* g_r   = ws+off; off += (size_t)N*256;
  float* e     = ws+off; off += (size_t)HN*N*N;      // e -> a1T (in-place transposed)
  float* gam   = ws+off; off += (size_t)HN*N*N;      // gaT (written transposed)
  float* partL = ws+off; off += (size_t)8*N*256;
  float* partG = ws+off; off += (size_t)8*N*256;
  float* pmin_f= ws+off; off += 16*128;
  float* pmax_f= ws+off; off += 16*128;
  float* pmin_g= ws+off; off += 16*256;
  float* pmax_g= ws+off; off += 16*256;
  float* fmn   = ws+off; off += 128;
  float* fmx   = ws+off; off += 128;
  float* gmn   = ws+off; off += 256;
  float* gmx   = ws+off; off += 256;
  float* nf    = ws+off; off += N;
  float* ng    = ws+off; off += (size_t)HN*N;
  float* mlA   = ws+off; off += (size_t)HN*N;
  float* islA  = ws+off; off += (size_t)HN*N;
  float* moA   = ws+off; off += (size_t)HN*N;
  float* isoA  = ws+off; off += (size_t)HN*N;
  float* maA   = ws+off; off += (size_t)HN*N;
  float* isaA  = ws+off; off += (size_t)HN*N;
  float* mgA   = ws+off; off += (size_t)HN*N;
  float* sgA   = ws+off; off += (size_t)HN*N;
  int* mask_l  = (int*)(ws+off); off += (size_t)HN*N;
  int* mask_g  = (int*)(ws+off); off += (size_t)HN*N;

  zero_ints<<<32, 256, 0, stream>>>(mask_l, 2*HN*N);

  gemm_lr<<<dim3(256,2), 256, 0, stream>>>(x, W_l, W_r, g_l, g_r);

  colmm_part<<<dim3(16,2), 256, 0, stream>>>(feats, g_r, pmin_f, pmax_f, pmin_g, pmax_g);
  colmm_fin <<<dim3(2),    256, 0, stream>>>(pmin_f, pmax_f, pmin_g, pmax_g, fmn, fmx, gmn, gmx);
  norms_kernel<<<dim3(N,2),256, 0, stream>>>(feats, g_r, fmn, fmx, gmn, gmx, nf, ng);

  compute_e<<<dim3(16,16,HN), 256, 0, stream>>>(g_l, g_r, attn_w, e);

  row_stats<<<dim3(N,HN), 256, 0, stream>>>(e, adj, nf, ng, mlA, islA, moA, isoA, maA, isaA, mgA, sgA);

  applyT<<<dim3(136,HN), 256, 0, stream>>>(e, gam, adj, nf, mlA, islA, moA, isoA, maA, isaA, ng);

  colselect3<<<dim3(N,HN,2), 256, 0, stream>>>(e, gam, mask_l, mask_g);

  attn_mm<<<dim3(16,HN,8), 256, 0, stream>>>(e, gam, g_r, mgA, sgA, mask_g, partL, partG);

  epilogue<<<N, 256, 0, stream>>>(partL, partG, mask_l, W_delta, b_delta, out);
}

// Round 6
// 218.664 us; speedup vs baseline: 1.3744x; 1.0499x over previous
//
#include <hip/hip_runtime.h>
#include <cstdint>
#include <cstddef>

#define N 1024
#define HN 4
#define FDIM 64
#define KSEL 512
#define FLT_MAX_ 3.402823466e+38f

// ---------------- reduction helpers (blockDim.x == 256) ----------------
__device__ __forceinline__ float wred_sum(float v){
#pragma unroll
  for(int o=32;o>0;o>>=1) v += __shfl_down(v,o,64);
  return v;
}
__device__ __forceinline__ float wred_max(float v){
#pragma unroll
  for(int o=32;o>0;o>>=1) v = fmaxf(v,__shfl_down(v,o,64));
  return v;
}
__device__ __forceinline__ float bred_sum(float v, float* scr){
  int t=threadIdx.x;
  v = wred_sum(v);
  __syncthreads();
  if((t&63)==0) scr[t>>6]=v;
  __syncthreads();
  return (scr[0]+scr[1])+(scr[2]+scr[3]);
}
__device__ __forceinline__ float bred_max(float v, float* scr){
  int t=threadIdx.x;
  v = wred_max(v);
  __syncthreads();
  if((t&63)==0) scr[t>>6]=v;
  __syncthreads();
  return fmaxf(fmaxf(scr[0],scr[1]),fmaxf(scr[2],scr[3]));
}

// ---------------- K0: zero masks ----------------
__global__ __launch_bounds__(256) void zero_ints(int* p, int n){
  int i = blockIdx.x*256 + threadIdx.x;
  if(i<n) p[i]=0;
}

// ---------------- K1: g = x@W ----------------
__global__ __launch_bounds__(256) void gemm_lr(const float* __restrict__ x,
                                               const float* __restrict__ W_l,
                                               const float* __restrict__ W_r,
                                               float* __restrict__ g_l,
                                               float* __restrict__ g_r){
  int i0 = blockIdx.x*4, t = threadIdx.x;
  const float* __restrict__ W = blockIdx.y ? W_r : W_l;
  float* __restrict__ g = blockIdx.y ? g_r : g_l;
  float acc[4] = {0.f,0.f,0.f,0.f};
#pragma unroll 8
  for(int k=0;k<256;k++){
    float w = W[(size_t)k*256 + t];
#pragma unroll
    for(int r=0;r<4;r++) acc[r] = fmaf(x[(size_t)(i0+r)*256 + k], w, acc[r]);
  }
#pragma unroll
  for(int r=0;r<4;r++) g[(size_t)(i0+r)*256 + t] = acc[r];
}

// ---------------- K2p/K2f/K2n: min/max + norms ----------------
__global__ __launch_bounds__(256) void colmm_part(const float* __restrict__ feats,
                                                  const float* __restrict__ g_r,
                                                  float* __restrict__ pmin_f, float* __restrict__ pmax_f,
                                                  float* __restrict__ pmin_g, float* __restrict__ pmax_g){
  int chunk = blockIdx.x, src = blockIdx.y, t = threadIdx.x;
  int cols = src ? 256 : 128;
  const float* in = src ? g_r : feats;
  if(t < cols){
    float lo = FLT_MAX_, hi = -FLT_MAX_;
    int r0 = chunk*64;
    for(int r=0;r<64;r++){
      float v = in[(size_t)(r0+r)*cols + t];
      lo = fminf(lo,v); hi = fmaxf(hi,v);
    }
    if(src){ pmin_g[chunk*256+t]=lo; pmax_g[chunk*256+t]=hi; }
    else   { pmin_f[chunk*128+t]=lo; pmax_f[chunk*128+t]=hi; }
  }
}

__global__ __launch_bounds__(256) void colmm_fin(const float* __restrict__ pmin_f, const float* __restrict__ pmax_f,
                                                 const float* __restrict__ pmin_g, const float* __restrict__ pmax_g,
                                                 float* __restrict__ fmn, float* __restrict__ fmx,
                                                 float* __restrict__ gmn, float* __restrict__ gmx){
  int src = blockIdx.x, t = threadIdx.x;
  int cols = src ? 256 : 128;
  if(t < cols){
    float lo = FLT_MAX_, hi = -FLT_MAX_;
    const float* pn = src ? pmin_g : pmin_f;
    const float* px = src ? pmax_g : pmax_f;
    for(int k=0;k<16;k++){
      lo = fminf(lo, pn[k*cols+t]);
      hi = fmaxf(hi, px[k*cols+t]);
    }
    if(src){ gmn[t]=lo; gmx[t]=hi; } else { fmn[t]=lo; fmx[t]=hi; }
  }
}

__global__ __launch_bounds__(256) void norms_kernel(const float* __restrict__ feats,
                                                    const float* __restrict__ g_r,
                                                    const float* __restrict__ fmn, const float* __restrict__ fmx,
                                                    const float* __restrict__ gmn, const float* __restrict__ gmx,
                                                    float* __restrict__ nf, float* __restrict__ ng){
  __shared__ float scr[4];
  int i = blockIdx.x, z = blockIdx.y, t = threadIdx.x;
  if(z==0){
    float u = 0.f;
    if(t < 128){
      float d = fmx[t]-fmn[t];
      float v = feats[(size_t)i*128 + t];
      u = (d==0.f) ? 0.f : (v - fmn[t])/d;
    }
    float tot = bred_sum(u*u, scr);
    if(t==0) nf[i] = sqrtf(tot);
  } else {
    int c = t, hh = t>>6;
    float d = gmx[c]-gmn[c];
    float v = g_r[(size_t)i*256 + c];
    float u = (v - gmn[c])/d;
    float ss = wred_sum(u*u);
    if((t&63)==0) ng[hh*N + i] = sqrtf(ss);
  }
}

// ---------------- K3: e[h][i][j], b128 LDS reads over f-chunks ----------------
__global__ __launch_bounds__(256) void compute_e(const float* __restrict__ g_l,
                                                 const float* __restrict__ g_r,
                                                 const float* __restrict__ attn_w,
                                                 float* __restrict__ e){
  __shared__ __align__(16) float grs[64][68];
  __shared__ __align__(16) float gls[64][68];
  __shared__ __align__(16) float aw[64], aw2[64];
  int h = blockIdx.z, i0 = blockIdx.y*64, j0 = blockIdx.x*64;
  int t = threadIdx.x;
  if(t < 64){ float w = attn_w[t]; aw[t]=w; aw2[t]=0.2f*w; }
#pragma unroll
  for(int k=0;k<16;k++){
    int idx = t + k*256; int r = idx>>6, f = idx&63;
    grs[r][f] = g_r[(size_t)(i0+r)*256 + h*64 + f];
    gls[r][f] = g_l[(size_t)(j0+r)*256 + h*64 + f];
  }
  __syncthreads();
  int tj = t&15, ti = t>>4;
  float acc[4][4];
#pragma unroll
  for(int a=0;a<4;a++)
#pragma unroll
    for(int b=0;b<4;b++) acc[a][b]=0.f;
  for(int fc=0; fc<64; fc+=4){
    float4 wv  = *(float4*)&aw[fc];
    float4 wv2 = *(float4*)&aw2[fc];
    float4 ga4[4], gb4[4];
#pragma unroll
    for(int a=0;a<4;a++) ga4[a] = *(float4*)&grs[ti*4+a][fc];
#pragma unroll
    for(int b=0;b<4;b++) gb4[b] = *(float4*)&gls[tj+16*b][fc];
#pragma unroll
    for(int a=0;a<4;a++)
#pragma unroll
      for(int b=0;b<4;b++){
        float s0 = ga4[a].x + gb4[b].x;
        float s1 = ga4[a].y + gb4[b].y;
        float s2 = ga4[a].z + gb4[b].z;
        float s3 = ga4[a].w + gb4[b].w;
        acc[a][b] = fmaf(s0, (s0>=0.f)?wv.x:wv2.x, acc[a][b]);
        acc[a][b] = fmaf(s1, (s1>=0.f)?wv.y:wv2.y, acc[a][b]);
        acc[a][b] = fmaf(s2, (s2>=0.f)?wv.z:wv2.z, acc[a][b]);
        acc[a][b] = fmaf(s3, (s3>=0.f)?wv.w:wv2.w, acc[a][b]);
      }
  }
#pragma unroll
  for(int a=0;a<4;a++)
#pragma unroll
    for(int b=0;b<4;b++){
      int i = i0 + ti*4 + a, j = j0 + tj + 16*b;
      e[((size_t)h*N + i)*N + j] = acc[a][b];
    }
}

// ---------------- K4: per-(h,i) row stats (reductions only) ----------------
__global__ __launch_bounds__(256) void row_stats(const float* __restrict__ e,
                                                 const int* __restrict__ adj,
                                                 const float* __restrict__ nf,
                                                 const float* __restrict__ ng,
                                                 float* __restrict__ mlA, float* __restrict__ islA,
                                                 float* __restrict__ moA, float* __restrict__ isoA,
                                                 float* __restrict__ maA, float* __restrict__ isaA,
                                                 float* __restrict__ mgA, float* __restrict__ sgA){
  __shared__ float es[1024];
  __shared__ float nfs[1024];
  __shared__ unsigned char adjs[1024];
  __shared__ float scr[4];
  int i = blockIdx.x, h = blockIdx.y, t = threadIdx.x;
  size_t base = ((size_t)h*N + i)*N;
  float ngv = ng[h*N + i];
#pragma unroll
  for(int k=0;k<4;k++){
    int j = t + k*256;
    es[j]  = e[base + j];
    nfs[j] = nf[j];
    adjs[j] = (adj[(size_t)i*N + j] > 0) ? 1 : 0;
  }
  __syncthreads();
  float ml=-FLT_MAX_, mo=-FLT_MAX_, ma=-FLT_MAX_;
#pragma unroll
  for(int k=0;k<4;k++){
    int j = t + k*256;
    float ev = es[j];
    mo = fmaxf(mo, ev);
    if(adjs[j]) ml = fmaxf(ml, ev);
    ma = fmaxf(ma, fabsf(nfs[j]-ngv));
  }
  ml = bred_max(ml, scr); mo = bred_max(mo, scr); ma = bred_max(ma, scr);
  float sl=0.f, so=0.f, sa=0.f;
#pragma unroll
  for(int k=0;k<4;k++){
    int j = t + k*256;
    float ev = es[j];
    so += __expf(ev-mo);
    if(adjs[j]) sl += __expf(ev-ml);
    sa += __expf(fabsf(nfs[j]-ngv)-ma);
  }
  sl = bred_sum(sl, scr); so = bred_sum(so, scr); sa = bred_sum(sa, scr);
  float isl = 1.f/sl, iso = 1.f/so, isa = 1.f/sa;
  float mg = -FLT_MAX_;
  float gloc[4];
#pragma unroll
  for(int k=0;k<4;k++){
    int j = t + k*256;
    float ev = es[j];
    float omega = __expf(ev-mo)*iso;
    float alpha = __expf(fabsf(nfs[j]-ngv)-ma)*isa;
    float g = 0.5f*(omega + 1.f - alpha);
    gloc[k] = g;
    mg = fmaxf(mg, g);
  }
  mg = bred_max(mg, scr);
  float sg = 0.f;
#pragma unroll
  for(int k=0;k<4;k++) sg += __expf((gloc[k]-mg)/1e-3f);
  sg = bred_sum(sg, scr);
  if(t==0){
    mlA[h*N+i]=ml; islA[h*N+i]=isl;
    moA[h*N+i]=mo; isoA[h*N+i]=iso;
    maA[h*N+i]=ma; isaA[h*N+i]=isa;
    mgA[h*N+i]=mg; sgA[h*N+i]=sg;
  }
}

// ---------------- K4b: applyT — elementwise a_1nd/gamma + transpose ----------------
// grid (136, HN): pairwise 64x64 tile transpose. e -> a1T in place; gamT written.
__global__ __launch_bounds__(256) void applyT(float* __restrict__ e,
                                              float* __restrict__ gamT,
                                              const int* __restrict__ adj,
                                              const float* __restrict__ nf,
                                              const float* __restrict__ mlA, const float* __restrict__ islA,
                                              const float* __restrict__ moA, const float* __restrict__ isoA,
                                              const float* __restrict__ maA, const float* __restrict__ isaA,
                                              const float* __restrict__ ng){
  __shared__ __align__(16) float buf1[64][65];   // gamma staging
  __shared__ __align__(16) float buf2[64][65];   // a1 of tile1
  __shared__ __align__(16) float buf3[64][65];   // a1 of tile2
  __shared__ float rml[64], risl[64], rmo[64], riso[64], rma[64], risa[64], rng[64], nfs[64];
  int h = blockIdx.y;
  int pp = blockIdx.x; int a = 0;
  while(pp >= 16 - a){ pp -= 16 - a; a++; }
  int b = a + pp;                 // a <= b
  int t = threadIdx.x;
  int rg = t >> 4, c4 = t & 15;

  // ---- phase 1: tile (a,b) ----
  int i0 = a*64, j0 = b*64;
  if(t < 64){
    int o = h*N + i0 + t;
    rml[t]=mlA[o]; risl[t]=islA[o]; rmo[t]=moA[o]; riso[t]=isoA[o];
    rma[t]=maA[o]; risa[t]=isaA[o]; rng[t]=ng[o]; nfs[t]=nf[j0+t];
  }
  __syncthreads();
  float4 ev[4]; int4 av[4];
#pragma unroll
  for(int k=0;k<4;k++){
    int row = rg*4+k;
    ev[k] = *(const float4*)(e + ((size_t)h*N + i0+row)*N + j0 + c4*4);
    av[k] = *(const int4*)(adj + (size_t)(i0+row)*N + j0 + c4*4);
  }
#pragma unroll
  for(int k=0;k<4;k++){
    int row = rg*4+k;
    float ml=rml[row], isl=risl[row], mo=rmo[row], iso=riso[row];
    float ma=rma[row], isa=risa[row], ngv=rng[row];
    float evc[4] = {ev[k].x,ev[k].y,ev[k].z,ev[k].w};
    int   avc[4] = {av[k].x,av[k].y,av[k].z,av[k].w};
#pragma unroll
    for(int c=0;c<4;c++){
      int j = c4*4+c;
      buf2[j][row] = (avc[c]>0) ? __expf(evc[c]-ml)*isl : 0.f;
      float omega = __expf(evc[c]-mo)*iso;
      float alpha = __expf(fabsf(nfs[j]-ngv)-ma)*isa;
      buf1[j][row] = 0.5f*(omega + 1.f - alpha);
    }
  }
  __syncthreads();
  // write gamma tile1 transposed -> gamT tile (b,a)
#pragma unroll
  for(int k=0;k<4;k++){
    int jr = rg*4+k;
    *(float4*)(gamT + ((size_t)h*N + j0+jr)*N + i0 + c4*4) = *(float4*)&buf1[jr][c4*4];
  }
  if(a == b){
#pragma unroll
    for(int k=0;k<4;k++){
      int jr = rg*4+k;
      *(float4*)(e + ((size_t)h*N + j0+jr)*N + i0 + c4*4) = *(float4*)&buf2[jr][c4*4];
    }
    return;
  }
  // ---- phase 2: tile (b,a) ----
  int i1 = b*64, j1 = a*64;
  __syncthreads();
  if(t < 64){
    int o = h*N + i1 + t;
    rml[t]=mlA[o]; risl[t]=islA[o]; rmo[t]=moA[o]; riso[t]=isoA[o];
    rma[t]=maA[o]; risa[t]=isaA[o]; rng[t]=ng[o]; nfs[t]=nf[j1+t];
  }
#pragma unroll
  for(int k=0;k<4;k++){
    int row = rg*4+k;
    ev[k] = *(const float4*)(e + ((size_t)h*N + i1+row)*N + j1 + c4*4);
    av[k] = *(const int4*)(adj + (size_t)(i1+row)*N + j1 + c4*4);
  }
  __syncthreads();
#pragma unroll
  for(int k=0;k<4;k++){
    int jr = rg*4+k;
    *(float4*)(e + ((size_t)h*N + i1+jr)*N + j1 + c4*4) = *(float4*)&buf2[jr][c4*4];
  }
#pragma unroll
  for(int k=0;k<4;k++){
    int row = rg*4+k;
    float ml=rml[row], isl=risl[row], mo=rmo[row], iso=riso[row];
    float ma=rma[row], isa=risa[row], ngv=rng[row];
    float evc[4] = {ev[k].x,ev[k].y,ev[k].z,ev[k].w};
    int   avc[4] = {av[k].x,av[k].y,av[k].z,av[k].w};
#pragma unroll
    for(int c=0;c<4;c++){
      int j = c4*4+c;
      buf3[j][row] = (avc[c]>0) ? __expf(evc[c]-ml)*isl : 0.f;
      float omega = __expf(evc[c]-mo)*iso;
      float alpha = __expf(fabsf(nfs[j]-ngv)-ma)*isa;
      buf1[j][row] = 0.5f*(omega + 1.f - alpha);
    }
  }
  __syncthreads();
#pragma unroll
  for(int k=0;k<4;k++){
    int jr = rg*4+k;
    *(float4*)(gamT + ((size_t)h*N + j1+jr)*N + i1 + c4*4) = *(float4*)&buf1[jr][c4*4];
    *(float4*)(e    + ((size_t)h*N + j1+jr)*N + i1 + c4*4) = *(float4*)&buf3[jr][c4*4];
  }
}

// ---------------- K5: exact top-512 select, one WAVE per column, zero barriers ----
// grid: 2048 blocks; wave w of block handles global column blockIdx.x*4+w.
// Column's 1024 values live in 16 regs/lane; hist is wave-private LDS.
__global__ __launch_bounds__(256) void colselect4(const float* __restrict__ a1T,
                                                  const float* __restrict__ gaT,
                                                  int* __restrict__ mask_l,
                                                  int* __restrict__ mask_g){
  __shared__ __align__(16) int hist[4][256];
  int t = threadIdx.x, w = t>>6, lane = t&63;
  int gcol = blockIdx.x*4 + w;            // 0..8191
  int z  = gcol >> 12;                    // 0: a1T, 1: gaT
  int hj = gcol & 4095;                   // h*N + j
  int h  = hj >> 10;
  const float* __restrict__ src = (z ? gaT : a1T) + (size_t)hj * (size_t)N;
  int* __restrict__ mask = z ? mask_g : mask_l;
  int* hw = hist[w];

  unsigned ur[16];
#pragma unroll
  for(int c=0;c<4;c++){
    uint4 u4 = ((const uint4*)src)[c*64 + lane];   // idx = c*256 + lane*4 + k
    ur[c*4+0]=u4.x; ur[c*4+1]=u4.y; ur[c*4+2]=u4.z; ur[c*4+3]=u4.w;
  }

  unsigned prefix = 0;
  int kth = KSEL, tiecnt = 0;
#pragma unroll
  for(int b=3;b>=0;b--){
    *(int4*)&hw[lane*4] = make_int4(0,0,0,0);
#pragma unroll
    for(int q=0;q<16;q++){
      unsigned u = ur[q];
      bool act = (b==3) || ((u >> (8*(b+1))) == prefix);
      if(act){
        int bucket = (u >> (8*b)) & 0xFF;
        unsigned long long mball = __ballot(true);
        int lead = __ffsll(mball) - 1;
        int maj = __shfl(bucket, lead, 64);
        if(bucket == maj){
          int cnt = (int)__popcll(__ballot(true));
          if(lane == lead) atomicAdd(&hw[maj], cnt);
        } else {
          atomicAdd(&hw[bucket], 1);
        }
      }
    }
    int4 hv = *(int4*)&hw[lane*4];        // lane owns bins 4l..4l+3
    int s = hv.x+hv.y+hv.z+hv.w;
    int P = s;
#pragma unroll
    for(int off=1; off<64; off<<=1){
      int q2 = __shfl_up(P, off, 64);
      if(lane >= off) P += q2;
    }
    int total = __shfl(P, 63, 64);
    int suffChunk  = total - (P - s);     // # vals in bins >= 4*lane
    int suffChunkN = total - P;           // # vals in bins >= 4*(lane+1)
    bool cross = (suffChunk >= kth) && (suffChunkN < kth);
    int selb=0, newk=0, tcnt=0;
    if(cross){
      int s3 = suffChunkN + hv.w;
      int s2 = s3 + hv.z;
      int s1 = s2 + hv.y;
      if(s3 >= kth){ selb=4*lane+3; newk = kth - suffChunkN; tcnt=hv.w; }
      else if(s2 >= kth){ selb=4*lane+2; newk = kth - s3; tcnt=hv.z; }
      else if(s1 >= kth){ selb=4*lane+1; newk = kth - s2; tcnt=hv.y; }
      else { selb=4*lane; newk = kth - s1; tcnt=hv.x; }
    }
    unsigned long long cm = __ballot(cross);
    int csrc = __ffsll(cm) - 1;
    selb   = __shfl(selb, csrc, 64);
    kth    = __shfl(newk, csrc, 64);
    tiecnt = __shfl(tcnt, csrc, 64);
    prefix = (prefix << 8) | (unsigned)selb;
  }

  unsigned T = prefix;
  int tneed = kth;
  if(tiecnt == tneed){
    // all ties accepted -> plain threshold
#pragma unroll
    for(int c=0;c<4;c++)
#pragma unroll
      for(int k2=0;k2<4;k2++){
        int i = c*256 + lane*4 + k2;
        if(ur[c*4+k2] >= T) mask[h*N + i] = 1;
      }
  } else {
    // index-ordered tie acceptance (lax.top_k semantics)
    int base = 0;
#pragma unroll
    for(int c=0;c<4;c++){
      int tc=0;
#pragma unroll
      for(int k2=0;k2<4;k2++) tc += (ur[c*4+k2]==T)?1:0;
      int pc = tc;
#pragma unroll
      for(int off=1; off<64; off<<=1){
        int q2 = __shfl_up(pc, off, 64);
        if(lane >= off) pc += q2;
      }
      int ctot = __shfl(pc, 63, 64);
      int run = base + pc - tc;
#pragma unroll
      for(int k2=0;k2<4;k2++){
        int i = c*256 + lane*4 + k2;
        unsigned u = ur[c*4+k2];
        bool sel = (u > T) || (u == T && run < tneed);
        run += (u==T)?1:0;
        if(sel) mask[h*N + i] = 1;
      }
      base += ctot;
    }
  }
}

// ---------------- K6: attn matmuls, transposed inputs + inline P transform ----------------
__global__ __launch_bounds__(256) void attn_mm(const float* __restrict__ a1T,
                                               const float* __restrict__ gaT,
                                               const float* __restrict__ g_r,
                                               const float* __restrict__ mgA,
                                               const float* __restrict__ sgA,
                                               const int* __restrict__ mask_g,
                                               float* __restrict__ partL,
                                               float* __restrict__ partG){
  __shared__ __align__(16) float a_t[32][68];
  __shared__ __align__(16) float p_t[32][68];
  __shared__ __align__(16) float b_s[32][68];
  __shared__ float mgv[64], isgv[64];
  __shared__ int mgf[64];
  int i0 = blockIdx.x*64, h = blockIdx.y, s = blockIdx.z, j0 = s*128;
  int t = threadIdx.x;
  if(t < 64){
    mgv[t]  = mgA[h*N + i0 + t];
    isgv[t] = 1.f / sgA[h*N + i0 + t];
    mgf[t]  = mask_g[h*N + i0 + t];
  }
  __syncthreads();
  int fq = t & 15, iq = t >> 4;
  float4 accL[4], accG[4];
#pragma unroll
  for(int r=0;r<4;r++){ accL[r]=make_float4(0,0,0,0); accG[r]=make_float4(0,0,0,0); }
  for(int sub=0; sub<4; sub++){
    int jb = j0 + sub*32;
#pragma unroll
    for(int k=0;k<2;k++){
      int idx = t + k*256;
      int jj = idx>>4, i4 = idx&15;
      size_t base = ((size_t)h*N + jb + jj)*N + i0 + i4*4;
      *(float4*)&a_t[jj][i4*4] = *(const float4*)(a1T + base);
      float4 g4 = *(const float4*)(gaT + base);
      int ii = i4*4;
      const float inv = 1.f/1024.f;
      float4 p4;
      p4.x = mgf[ii+0] ? __expf((g4.x - mgv[ii+0])/1e-3f)*isgv[ii+0] : inv;
      p4.y = mgf[ii+1] ? __expf((g4.y - mgv[ii+1])/1e-3f)*isgv[ii+1] : inv;
      p4.z = mgf[ii+2] ? __expf((g4.z - mgv[ii+2])/1e-3f)*isgv[ii+2] : inv;
      p4.w = mgf[ii+3] ? __expf((g4.w - mgv[ii+3])/1e-3f)*isgv[ii+3] : inv;
      *(float4*)&p_t[jj][i4*4] = p4;
      *(float4*)&b_s[jj][i4*4] = *(const float4*)(g_r + (size_t)(jb+jj)*256 + h*64 + i4*4);
    }
    __syncthreads();
#pragma unroll 4
    for(int j=0;j<32;j++){
      float4 bv = *(float4*)&b_s[j][fq*4];
      float4 av = *(float4*)&a_t[j][iq*4];
      float4 pv = *(float4*)&p_t[j][iq*4];
      accL[0].x = fmaf(av.x, bv.x, accL[0].x); accL[0].y = fmaf(av.x, bv.y, accL[0].y);
      accL[0].z = fmaf(av.x, bv.z, accL[0].z); accL[0].w = fmaf(av.x, bv.w, accL[0].w);
      accL[1].x = fmaf(av.y, bv.x, accL[1].x); accL[1].y = fmaf(av.y, bv.y, accL[1].y);
      accL[1].z = fmaf(av.y, bv.z, accL[1].z); accL[1].w = fmaf(av.y, bv.w, accL[1].w);
      accL[2].x = fmaf(av.z, bv.x, accL[2].x); accL[2].y = fmaf(av.z, bv.y, accL[2].y);
      accL[2].z = fmaf(av.z, bv.z, accL[2].z); accL[2].w = fmaf(av.z, bv.w, accL[2].w);
      accL[3].x = fmaf(av.w, bv.x, accL[3].x); accL[3].y = fmaf(av.w, bv.y, accL[3].y);
      accL[3].z = fmaf(av.w, bv.z, accL[3].z); accL[3].w = fmaf(av.w, bv.w, accL[3].w);
      accG[0].x = fmaf(pv.x, bv.x, accG[0].x); accG[0].y = fmaf(pv.x, bv.y, accG[0].y);
      accG[0].z = fmaf(pv.x, bv.z, accG[0].z); accG[0].w = fmaf(pv.x, bv.w, accG[0].w);
      accG[1].x = fmaf(pv.y, bv.x, accG[1].x); accG[1].y = fmaf(pv.y, bv.y, accG[1].y);
      accG[1].z = fmaf(pv.y, bv.z, accG[1].z); accG[1].w = fmaf(pv.y, bv.w, accG[1].w);
      accG[2].x = fmaf(pv.z, bv.x, accG[2].x); accG[2].y = fmaf(pv.z, bv.y, accG[2].y);
      accG[2].z = fmaf(pv.z, bv.z, accG[2].z); accG[2].w = fmaf(pv.z, bv.w, accG[2].w);
      accG[3].x = fmaf(pv.w, bv.x, accG[3].x); accG[3].y = fmaf(pv.w, bv.y, accG[3].y);
      accG[3].z = fmaf(pv.w, bv.z, accG[3].z); accG[3].w = fmaf(pv.w, bv.w, accG[3].w);
    }
    __syncthreads();
  }
#pragma unroll
  for(int r=0;r<4;r++){
    int i = i0 + iq*4 + r;
    size_t o = ((size_t)s*N + i)*256 + h*64 + fq*4;
    *(float4*)&partL[o] = accL[r];
    *(float4*)&partG[o] = accG[r];
  }
}

// ---------------- K7: reduce partials + delta-gate epilogue ----------------
__global__ __launch_bounds__(256) void epilogue(const float* __restrict__ partL,
                                                const float* __restrict__ partG,
                                                const int* __restrict__ mask_l,
                                                const float* __restrict__ W_delta,
                                                const float* __restrict__ b_delta,
                                                float* __restrict__ out){
  __shared__ float cat[4][128];
  __shared__ float inter_s[4][64];
  int i = blockIdx.x, t = threadIdx.x;
  int h = t>>6, f = t&63;
  float sl = 0.f, sg = 0.f;
#pragma unroll
  for(int s2=0;s2<8;s2++){
    size_t o = ((size_t)s2*N + i)*256 + h*64 + f;
    sl += partL[o];
    sg += partG[o];
  }
  if(!mask_l[h*N + i]) sl = 0.f;
  cat[h][f]      = sl;
  cat[h][64 + f] = sg;
  __syncthreads();
  float d = b_delta[f];
  for(int c=0;c<128;c++) d = fmaf(cat[h][c], W_delta[(size_t)c*64 + f], d);
  d = (d >= 0.f) ? d : 0.2f*d;
  inter_s[h][f] = d;
  __syncthreads();
  float m = inter_s[0][f];
#pragma unroll
  for(int hh=1;hh<4;hh++) m = fmaxf(m, inter_s[hh][f]);
  float ssum = 0.f;
#pragma unroll
  for(int hh=0;hh<4;hh++) ssum += __expf(inter_s[hh][f]-m);
  float delta = __expf(d - m)/ssum;
  out[(size_t)i*256 + h*64 + f] = delta*sl + (1.f - delta)*sg;
}

// ---------------- launch ----------------
extern "C" void kernel_launch(void* const* d_in, const int* in_sizes, int n_in,
                              void* d_out, int out_size, void* d_ws, size_t ws_size,
                              hipStream_t stream) {
  const float* feats  = (const float*)d_in[0];
  const float* x      = (const float*)d_in[1];
  const int*   adj    = (const int*)  d_in[2];
  const float* W_l    = (const float*)d_in[3];
  const float* W_r    = (const float*)d_in[4];
  const float* attn_w = (const float*)d_in[5];
  const float* W_delta= (const float*)d_in[6];
  const float* b_delta= (const float*)d_in[7];
  float* out = (float*)d_out;

  float* ws = (float*)d_ws;
  size_t off = 0;
  float* g_l   = ws+off; off += (size_t)N*256;
  float* g_r   = ws+off; off += (size_t)N*256;
  float* e     = ws+off; off += (size_t)HN*N*N;      // e -> a1T (in-place transposed)
  float* gam   = ws+off; off += (size_t)HN*N*N;      // gaT (written transposed)
  float* partL = ws+off; off += (size_t)8*N*256;
  float* partG = ws+off; off += (size_t)8*N*256;
  float* pmin_f= ws+off; off += 16*128;
  float* pmax_f= ws+off; off += 16*128;
  float* pmin_g= ws+off; off += 16*256;
  float* pmax_g= ws+off; off += 16*256;
  float* fmn   = ws+off; off += 128;
  float* fmx   = ws+off; off += 128;
  float* gmn   = ws+off; off += 256;
  float* gmx   = ws+off; off += 256;
  float* nf    = ws+off; off += N;
  float* ng    = ws+off; off += (size_t)HN*N;
  float* mlA   = ws+off; off += (size_t)HN*N;
  float* islA  = ws+off; off += (size_t)HN*N;
  float* moA   = ws+off; off += (size_t)HN*N;
  float* isoA  = ws+off; off += (size_t)HN*N;
  float* maA   = ws+off; off += (size_t)HN*N;
  float* isaA  = ws+off; off += (size_t)HN*N;
  float* mgA   = ws+off; off += (size_t)HN*N;
  float* sgA   = ws+off; off += (size_t)HN*N;
  int* mask_l  = (int*)(ws+off); off += (size_t)HN*N;
  int* mask_g  = (int*)(ws+off); off += (size_t)HN*N;

  zero_ints<<<32, 256, 0, stream>>>(mask_l, 2*HN*N);

  gemm_lr<<<dim3(256,2), 256, 0, stream>>>(x, W_l, W_r, g_l, g_r);

  colmm_part<<<dim3(16,2), 256, 0, stream>>>(feats, g_r, pmin_f, pmax_f, pmin_g, pmax_g);
  colmm_fin <<<dim3(2),    256, 0, stream>>>(pmin_f, pmax_f, pmin_g, pmax_g, fmn, fmx, gmn, gmx);
  norms_kernel<<<dim3(N,2),256, 0, stream>>>(feats, g_r, fmn, fmx, gmn, gmx, nf, ng);

  compute_e<<<dim3(16,16,HN), 256, 0, stream>>>(g_l, g_r, attn_w, e);

  row_stats<<<dim3(N,HN), 256, 0, stream>>>(e, adj, nf, ng, mlA, islA, moA, isoA, maA, isaA, mgA, sgA);

  applyT<<<dim3(136,HN), 256, 0, stream>>>(e, gam, adj, nf, mlA, islA, moA, isoA, maA, isaA, ng);

  colselect4<<<2048, 256, 0, stream>>>(e, gam, mask_l, mask_g);

  attn_mm<<<dim3(16,HN,8), 256, 0, stream>>>(e, gam, g_r, mgA, sgA, mask_g, partL, partG);

  epilogue<<<N, 256, 0, stream>>>(partL, partG, mask_l, W_delta, b_delta, out);
}